// Round 1
// baseline (246.179 us; speedup 1.0000x reference)
//
#include <hip/hip_runtime.h>
#include <stdint.h>

#define B_ 8
#define T_ 1024
#define C_ 1024
#define H_ 16
#define HD 64
#define M_TOT (B_ * T_)  // 8192

using f32x4 = __attribute__((ext_vector_type(4))) float;
using s16x8 = __attribute__((ext_vector_type(8))) short;

__device__ __forceinline__ unsigned short f2bf(float f) {
  unsigned int u = __builtin_bit_cast(unsigned int, f);
  unsigned int r = (u + 0x7fffu + ((u >> 16) & 1u)) >> 16;
  return (unsigned short)r;
}

__device__ __forceinline__ void gload_lds16(const void* g, void* l) {
  __builtin_amdgcn_global_load_lds(
      (const __attribute__((address_space(1))) unsigned int*)g,
      (__attribute__((address_space(3))) unsigned int*)l, 16, 0, 0);
}

// ---------------------------------------------------------------- convert
__global__ __launch_bounds__(256) void k_convert(
    const float* __restrict__ x, const float* __restrict__ wq,
    const float* __restrict__ wk, const float* __restrict__ wv,
    const float* __restrict__ wp, const float* __restrict__ bq,
    const float* __restrict__ bk, const float* __restrict__ bv,
    unsigned short* __restrict__ xb, unsigned short* __restrict__ wqkv,
    unsigned short* __restrict__ wpb, float* __restrict__ bias_cat) {
  const long n_x = (long)M_TOT * C_;          // 8388608
  const long W_ELT = (long)C_ * C_;           // 1048576
  const long total4 = (n_x + 4 * W_ELT) >> 2; // 3145728
  for (long i4 = (long)blockIdx.x * blockDim.x + threadIdx.x; i4 < total4;
       i4 += (long)gridDim.x * blockDim.x) {
    long i = i4 << 2;
    const float* src;
    unsigned short* dst;
    if (i < n_x) {
      src = x + i;
      dst = xb + i;
    } else {
      long off = i - n_x;
      int which = (int)(off >> 20);
      long wo = off & (W_ELT - 1);
      if (which < 3) {
        src = (which == 0 ? wq : which == 1 ? wk : wv) + wo;
        dst = wqkv + which * W_ELT + wo;
      } else {
        src = wp + wo;
        dst = wpb + wo;
      }
    }
    float4 v = *(const float4*)src;
    ushort4 u;
    u.x = f2bf(v.x); u.y = f2bf(v.y); u.z = f2bf(v.z); u.w = f2bf(v.w);
    *(ushort4*)dst = u;
  }
  int t = blockIdx.x * blockDim.x + threadIdx.x;
  if (t < 3 * C_) {
    float v = t < C_ ? bq[t] : (t < 2 * C_ ? bk[t - C_] : bv[t - 2 * C_]);
    bias_cat[t] = v;
  }
}

// ---------------------------------------------------------------- GEMM (A @ B^T)
// A: [M][1024] bf16 row-major; Bm: [N][1024] bf16 row-major.
// EPI 0: QKV epilogue (bias, Q scaled 1/8, K [B,H,T,64], V transposed [B,H,64,T])
// EPI 1: proj epilogue (bias + residual -> f32 z)
#define BM 128
#define BN 128
#define BK 32

template <int EPI>
__global__ __launch_bounds__(256, 2) void k_gemm(
    const unsigned short* __restrict__ A, const unsigned short* __restrict__ Bm,
    const float* __restrict__ bias, unsigned short* __restrict__ q_ws,
    unsigned short* __restrict__ k_ws, unsigned short* __restrict__ vt_ws,
    const float* __restrict__ xres, float* __restrict__ zout) {
  __shared__ unsigned short Al[BM * BK];  // 8 KB
  __shared__ unsigned short Bl[BN * BK];  // 8 KB
  const int tid = threadIdx.x, lane = tid & 63, w = tid >> 6;
  const int lc = lane & 15, lr = lane >> 4;
  const int m0 = blockIdx.y * BM, n0 = blockIdx.x * BN;
  const int wr = w >> 1, wc = w & 1;
  const char* Ab = (const char*)A;
  const char* Bb = (const char*)Bm;

  f32x4 acc[4][4] = {};

  for (int k0 = 0; k0 < C_; k0 += BK) {
#pragma unroll
    for (int it = 0; it < 2; ++it) {
      int f = it * 4096 + tid * 16;
      int row = f >> 6, colb = f & 63;
      gload_lds16(Ab + (long)(m0 + row) * (C_ * 2) + k0 * 2 + colb,
                  (char*)Al + it * 4096 + w * 1024);
      gload_lds16(Bb + (long)(n0 + row) * (C_ * 2) + k0 * 2 + colb,
                  (char*)Bl + it * 4096 + w * 1024);
    }
    __syncthreads();
    s16x8 af[4], bfr[4];
#pragma unroll
    for (int mf = 0; mf < 4; ++mf)
      af[mf] = *(const s16x8*)&Al[(wr * 64 + mf * 16 + lc) * BK + lr * 8];
#pragma unroll
    for (int nf = 0; nf < 4; ++nf)
      bfr[nf] = *(const s16x8*)&Bl[(wc * 64 + nf * 16 + lc) * BK + lr * 8];
#pragma unroll
    for (int mf = 0; mf < 4; ++mf)
#pragma unroll
      for (int nf = 0; nf < 4; ++nf)
        acc[mf][nf] = __builtin_amdgcn_mfma_f32_16x16x32_bf16(af[mf], bfr[nf],
                                                              acc[mf][nf], 0, 0, 0);
    __syncthreads();
  }

  if (EPI == 0) {
#pragma unroll
    for (int mf = 0; mf < 4; ++mf)
#pragma unroll
      for (int nf = 0; nf < 4; ++nf) {
        int gn = n0 + wc * 64 + nf * 16 + lc;
        int which = gn >> 10, nn = gn & 1023;
        int hh = nn >> 6, dd = nn & 63;
        float bia = bias[gn];
        if (which == 2) {
          int gm = m0 + wr * 64 + mf * 16 + lr * 4;
          int bb = gm >> 10, tt = gm & 1023;
          ushort4 pk;
          pk.x = f2bf(acc[mf][nf][0] + bia);
          pk.y = f2bf(acc[mf][nf][1] + bia);
          pk.z = f2bf(acc[mf][nf][2] + bia);
          pk.w = f2bf(acc[mf][nf][3] + bia);
          *(ushort4*)&vt_ws[((long)(bb * H_ + hh) * HD + dd) * T_ + tt] = pk;
        } else {
          unsigned short* dst = (which == 0) ? q_ws : k_ws;
          float scl = (which == 0) ? 0.125f : 1.0f;
#pragma unroll
          for (int i = 0; i < 4; ++i) {
            int gm = m0 + wr * 64 + mf * 16 + lr * 4 + i;
            int bb = gm >> 10, tt = gm & 1023;
            dst[((long)(bb * H_ + hh) * T_ + tt) * HD + dd] =
                f2bf((acc[mf][nf][i] + bia) * scl);
          }
        }
      }
  } else {
#pragma unroll
    for (int mf = 0; mf < 4; ++mf)
#pragma unroll
      for (int nf = 0; nf < 4; ++nf) {
        int gn = n0 + wc * 64 + nf * 16 + lc;
        float bia = bias[gn];
#pragma unroll
        for (int i = 0; i < 4; ++i) {
          int gm = m0 + wr * 64 + mf * 16 + lr * 4 + i;
          long idx = (long)gm * C_ + gn;
          zout[idx] = acc[mf][nf][i] + bia + xres[idx];
        }
      }
  }
}

// ---------------------------------------------------------------- attention
// Q,K: [B*H][T][64] bf16 (Q pre-scaled by 1/8). Vt: [B*H][64][T] bf16.
// Block: 4 waves x 16 q-rows = 64 q-rows. Key tiles of 64, K/Vt staged in
// swizzled LDS (byte ^= (row&7)<<4; source pre-swizzled for global_load_lds).
__global__ __launch_bounds__(256, 2) void k_attn(
    const unsigned short* __restrict__ Qp, const unsigned short* __restrict__ Kp,
    const unsigned short* __restrict__ Vtp, const int* __restrict__ maskp,
    unsigned short* __restrict__ Yp) {
  __shared__ unsigned short Kl[64 * 64];     // 8 KB, [key][d] swizzled
  __shared__ unsigned short Vl[64 * 64];     // 8 KB, [d][key] swizzled
  __shared__ unsigned short Pl[4][16 * 64];  // 2 KB per wave, [q][key] swizzled
  const int tid = threadIdx.x, lane = tid & 63, w = tid >> 6;
  const int bh = blockIdx.x >> 4, qt = blockIdx.x & 15;
  const int b = bh >> 4, h = bh & 15;
  const int lc = lane & 15, lr = lane >> 4;
  const int q0 = qt * 64 + w * 16;

  const unsigned short* qbase = Qp + ((long)bh * T_ + q0) * HD;
  s16x8 aq0 = *(const s16x8*)(qbase + lc * HD + lr * 8);
  s16x8 aq1 = *(const s16x8*)(qbase + lc * HD + 32 + lr * 8);

  float m_run[4], l_run[4];
  f32x4 o[4] = {};
#pragma unroll
  for (int i = 0; i < 4; ++i) { m_run[i] = -3e38f; l_run[i] = 0.f; }

  const char* kb_g = (const char*)(Kp + (long)bh * T_ * HD);
  const char* vb_g = (const char*)(Vtp + (long)bh * HD * T_);
  const int* mrow = maskp + b * T_;

  for (int kt = 0; kt < T_ / 64; ++kt) {
    // stage K tile (8KB contiguous) and Vt tile (64 rows of 128B, stride 2048B)
#pragma unroll
    for (int it = 0; it < 2; ++it) {
      int f = it * 4096 + w * 1024 + lane * 16;
      int row = f >> 7, inrow = f & 127;
      int swz = inrow ^ ((row & 7) << 4);
      gload_lds16(kb_g + (long)kt * 8192 + (f & ~127) + swz,
                  (char*)Kl + it * 4096 + w * 1024);
      gload_lds16(vb_g + (long)row * (T_ * 2) + kt * 128 + swz,
                  (char*)Vl + it * 4096 + w * 1024);
    }
    __syncthreads();

    // S = Q K^T  (C layout: col=key (lc), row=q (lr*4+i)); Q already has 1/8
    f32x4 s[4];
#pragma unroll
    for (int kf = 0; kf < 4; ++kf) {
      int key = kf * 16 + lc;
      s16x8 kb0 = *(const s16x8*)((const char*)Kl +
                                  ((key * 128 + lr * 16) ^ ((key & 7) << 4)));
      s16x8 kb1 = *(const s16x8*)((const char*)Kl +
                                  ((key * 128 + 64 + lr * 16) ^ ((key & 7) << 4)));
      f32x4 z = {};
      z = __builtin_amdgcn_mfma_f32_16x16x32_bf16(aq0, kb0, z, 0, 0, 0);
      z = __builtin_amdgcn_mfma_f32_16x16x32_bf16(aq1, kb1, z, 0, 0, 0);
      int mv = mrow[kt * 64 + key];
#pragma unroll
      for (int i = 0; i < 4; ++i) s[kf][i] = mv ? z[i] : -1e9f;
    }

    // online softmax (rows live in reg i, cols across 16 lanes x 4 frags)
#pragma unroll
    for (int i = 0; i < 4; ++i) {
      float t0 = fmaxf(fmaxf(s[0][i], s[1][i]), fmaxf(s[2][i], s[3][i]));
#pragma unroll
      for (int d = 1; d < 16; d <<= 1) t0 = fmaxf(t0, __shfl_xor(t0, d, 64));
      float mn = fmaxf(m_run[i], t0);
      float sc = __expf(m_run[i] - mn);
      m_run[i] = mn;
      l_run[i] *= sc;
#pragma unroll
      for (int nf = 0; nf < 4; ++nf) o[nf][i] *= sc;
      float ps = 0.f;
#pragma unroll
      for (int kf = 0; kf < 4; ++kf) {
        float pv = __expf(s[kf][i] - mn);
        s[kf][i] = pv;
        ps += pv;
      }
#pragma unroll
      for (int d = 1; d < 16; d <<= 1) ps += __shfl_xor(ps, d, 64);
      l_run[i] += ps;
    }

    // P -> LDS (bf16, swizzled), then PV MFMAs
    unsigned short* pw = Pl[w];
#pragma unroll
    for (int kf = 0; kf < 4; ++kf) {
      int key2 = (kf * 16 + lc) * 2;
#pragma unroll
      for (int i = 0; i < 4; ++i) {
        int row = lr * 4 + i;
        *(unsigned short*)((char*)pw + ((row * 128 + key2) ^ ((row & 7) << 4))) =
            f2bf(s[kf][i]);
      }
    }
#pragma unroll
    for (int kc = 0; kc < 2; ++kc) {
      int koff = kc * 64 + lr * 16;
      s16x8 ap = *(const s16x8*)((const char*)pw +
                                 ((lc * 128 + koff) ^ ((lc & 7) << 4)));
#pragma unroll
      for (int nf = 0; nf < 4; ++nf) {
        int drow = nf * 16 + lc;
        s16x8 vb = *(const s16x8*)((const char*)Vl +
                                   ((drow * 128 + koff) ^ ((drow & 7) << 4)));
        o[nf] = __builtin_amdgcn_mfma_f32_16x16x32_bf16(ap, vb, o[nf], 0, 0, 0);
      }
    }
    __syncthreads();
  }

  // normalize + write y [B,T,C] bf16
  unsigned short* yb = Yp + ((long)(b * T_ + q0)) * C_ + h * 64;
#pragma unroll
  for (int nf = 0; nf < 4; ++nf) {
    int d = nf * 16 + lc;
#pragma unroll
    for (int i = 0; i < 4; ++i) {
      int qrow = lr * 4 + i;
      yb[(long)qrow * C_ + d] = f2bf(o[nf][i] / l_run[i]);
    }
  }
}

// ---------------------------------------------------------------- LayerNorm
__global__ __launch_bounds__(256) void k_ln(const float* __restrict__ z,
                                            const float* __restrict__ lw,
                                            const float* __restrict__ lb,
                                            float* __restrict__ out) {
  const int row = blockIdx.x;
  float4 v = ((const float4*)(z + (long)row * C_))[threadIdx.x];
  float s = v.x + v.y + v.z + v.w;
  float s2 = v.x * v.x + v.y * v.y + v.z * v.z + v.w * v.w;
#pragma unroll
  for (int d = 1; d < 64; d <<= 1) {
    s += __shfl_xor(s, d, 64);
    s2 += __shfl_xor(s2, d, 64);
  }
  __shared__ float rs[4], rq[4];
  int wv_ = threadIdx.x >> 6;
  if ((threadIdx.x & 63) == 0) { rs[wv_] = s; rq[wv_] = s2; }
  __syncthreads();
  s = rs[0] + rs[1] + rs[2] + rs[3];
  s2 = rq[0] + rq[1] + rq[2] + rq[3];
  float mu = s * (1.0f / C_);
  float var = s2 * (1.0f / C_) - mu * mu;
  float inv = rsqrtf(var + 1e-12f);
  float4 wv4 = ((const float4*)lw)[threadIdx.x];
  float4 bv4 = ((const float4*)lb)[threadIdx.x];
  float4 ov;
  ov.x = (v.x - mu) * inv * wv4.x + bv4.x;
  ov.y = (v.y - mu) * inv * wv4.y + bv4.y;
  ov.z = (v.z - mu) * inv * wv4.z + bv4.z;
  ov.w = (v.w - mu) * inv * wv4.w + bv4.w;
  ((float4*)(out + (long)row * C_))[threadIdx.x] = ov;
}

// ---------------------------------------------------------------- launch
extern "C" void kernel_launch(void* const* d_in, const int* in_sizes, int n_in,
                              void* d_out, int out_size, void* d_ws,
                              size_t ws_size, hipStream_t stream) {
  const float* x = (const float*)d_in[0];
  const int* mask = (const int*)d_in[1];
  const float* Wq = (const float*)d_in[2];
  const float* bq = (const float*)d_in[3];
  const float* Wk = (const float*)d_in[4];
  const float* bk = (const float*)d_in[5];
  const float* Wv = (const float*)d_in[6];
  const float* bv = (const float*)d_in[7];
  const float* Wp = (const float*)d_in[8];
  const float* bp = (const float*)d_in[9];
  const float* lnw = (const float*)d_in[10];
  const float* lnb = (const float*)d_in[11];
  float* out = (float*)d_out;

  char* ws = (char*)d_ws;
  const size_t MB = 1024 * 1024;
  unsigned short* xb = (unsigned short*)(ws);             // 16 MB
  unsigned short* q_ws = (unsigned short*)(ws + 16 * MB); // 16 MB
  unsigned short* k_ws = (unsigned short*)(ws + 32 * MB); // 16 MB
  unsigned short* vt_ws = (unsigned short*)(ws + 48 * MB);// 16 MB
  unsigned short* y_ws = (unsigned short*)(ws + 64 * MB); // 16 MB
  unsigned short* wqkv = (unsigned short*)(ws + 80 * MB); // 6 MB
  unsigned short* wpb = (unsigned short*)(ws + 86 * MB);  // 2 MB
  float* bias_cat = (float*)(ws + 88 * MB);               // 12 KB
  float* z = (float*)(ws);  // 32 MB, aliases xb+q_ws (both dead by then)

  k_convert<<<dim3(2048), dim3(256), 0, stream>>>(x, Wq, Wk, Wv, Wp, bq, bk, bv,
                                                  xb, wqkv, wpb, bias_cat);
  k_gemm<0><<<dim3(24, 64), dim3(256), 0, stream>>>(
      xb, wqkv, bias_cat, q_ws, k_ws, vt_ws, nullptr, nullptr);
  k_attn<<<dim3(2048), dim3(256), 0, stream>>>(q_ws, k_ws, vt_ws, mask, y_ws);
  k_gemm<1><<<dim3(8, 64), dim3(256), 0, stream>>>(
      y_ws, wpb, bp, nullptr, nullptr, nullptr, x, z);
  k_ln<<<dim3(8192), dim3(256), 0, stream>>>(z, lnw, lnb, out);
}

// Round 2
// 208.795 us; speedup vs baseline: 1.1790x; 1.1790x over previous
//
#include <hip/hip_runtime.h>
#include <stdint.h>

#define B_ 8
#define T_ 1024
#define C_ 1024
#define H_ 16
#define HD 64
#define M_TOT (B_ * T_)  // 8192

using f32x4 = __attribute__((ext_vector_type(4))) float;
using s16x8 = __attribute__((ext_vector_type(8))) short;

__device__ __forceinline__ unsigned short f2bf(float f) {
  unsigned int u = __builtin_bit_cast(unsigned int, f);
  unsigned int r = (u + 0x7fffu + ((u >> 16) & 1u)) >> 16;
  return (unsigned short)r;
}

__device__ __forceinline__ void gload_lds16(const void* g, void* l) {
  __builtin_amdgcn_global_load_lds(
      (const __attribute__((address_space(1))) unsigned int*)g,
      (__attribute__((address_space(3))) unsigned int*)l, 16, 0, 0);
}

// ---------------------------------------------------------------- convert
__global__ __launch_bounds__(256) void k_convert(
    const float* __restrict__ x, const float* __restrict__ wq,
    const float* __restrict__ wk, const float* __restrict__ wv,
    const float* __restrict__ wp, const float* __restrict__ bq,
    const float* __restrict__ bk, const float* __restrict__ bv,
    unsigned short* __restrict__ xb, unsigned short* __restrict__ wqkv,
    unsigned short* __restrict__ wpb, float* __restrict__ bias_cat) {
  const long n_x = (long)M_TOT * C_;          // 8388608
  const long W_ELT = (long)C_ * C_;           // 1048576
  const long total4 = (n_x + 4 * W_ELT) >> 2; // 3145728
  for (long i4 = (long)blockIdx.x * blockDim.x + threadIdx.x; i4 < total4;
       i4 += (long)gridDim.x * blockDim.x) {
    long i = i4 << 2;
    const float* src;
    unsigned short* dst;
    if (i < n_x) {
      src = x + i;
      dst = xb + i;
    } else {
      long off = i - n_x;
      int which = (int)(off >> 20);
      long wo = off & (W_ELT - 1);
      if (which < 3) {
        src = (which == 0 ? wq : which == 1 ? wk : wv) + wo;
        dst = wqkv + which * W_ELT + wo;
      } else {
        src = wp + wo;
        dst = wpb + wo;
      }
    }
    float4 v = *(const float4*)src;
    ushort4 u;
    u.x = f2bf(v.x); u.y = f2bf(v.y); u.z = f2bf(v.z); u.w = f2bf(v.w);
    *(ushort4*)dst = u;
  }
  int t = blockIdx.x * blockDim.x + threadIdx.x;
  if (t < 3 * C_) {
    float v = t < C_ ? bq[t] : (t < 2 * C_ ? bk[t - C_] : bv[t - 2 * C_]);
    bias_cat[t] = v;
  }
}

// ---------------------------------------------------------------- GEMM (A @ B^T)
#define BM 128
#define BN 128
#define BK 32

template <int EPI>
__global__ __launch_bounds__(256, 2) void k_gemm(
    const unsigned short* __restrict__ A, const unsigned short* __restrict__ Bm,
    const float* __restrict__ bias, unsigned short* __restrict__ q_ws,
    unsigned short* __restrict__ k_ws, unsigned short* __restrict__ vt_ws,
    const float* __restrict__ xres, float* __restrict__ zout) {
  __shared__ unsigned short Al[BM * BK];  // 8 KB
  __shared__ unsigned short Bl[BN * BK];  // 8 KB
  const int tid = threadIdx.x, lane = tid & 63, w = tid >> 6;
  const int lc = lane & 15, lr = lane >> 4;
  const int m0 = blockIdx.y * BM, n0 = blockIdx.x * BN;
  const int wr = w >> 1, wc = w & 1;
  const char* Ab = (const char*)A;
  const char* Bb = (const char*)Bm;

  f32x4 acc[4][4] = {};

  for (int k0 = 0; k0 < C_; k0 += BK) {
#pragma unroll
    for (int it = 0; it < 2; ++it) {
      int f = it * 4096 + tid * 16;
      int row = f >> 6, colb = f & 63;
      gload_lds16(Ab + (long)(m0 + row) * (C_ * 2) + k0 * 2 + colb,
                  (char*)Al + it * 4096 + w * 1024);
      gload_lds16(Bb + (long)(n0 + row) * (C_ * 2) + k0 * 2 + colb,
                  (char*)Bl + it * 4096 + w * 1024);
    }
    __syncthreads();
    s16x8 af[4], bfr[4];
#pragma unroll
    for (int mf = 0; mf < 4; ++mf)
      af[mf] = *(const s16x8*)&Al[(wr * 64 + mf * 16 + lc) * BK + lr * 8];
#pragma unroll
    for (int nf = 0; nf < 4; ++nf)
      bfr[nf] = *(const s16x8*)&Bl[(wc * 64 + nf * 16 + lc) * BK + lr * 8];
#pragma unroll
    for (int mf = 0; mf < 4; ++mf)
#pragma unroll
      for (int nf = 0; nf < 4; ++nf)
        acc[mf][nf] = __builtin_amdgcn_mfma_f32_16x16x32_bf16(af[mf], bfr[nf],
                                                              acc[mf][nf], 0, 0, 0);
    __syncthreads();
  }

  if (EPI == 0) {
    // Q gets 1/8 (scale) * log2(e) so attention can use exp2 directly
#pragma unroll
    for (int mf = 0; mf < 4; ++mf)
#pragma unroll
      for (int nf = 0; nf < 4; ++nf) {
        int gn = n0 + wc * 64 + nf * 16 + lc;
        int which = gn >> 10, nn = gn & 1023;
        int hh = nn >> 6, dd = nn & 63;
        float bia = bias[gn];
        if (which == 2) {
          int gm = m0 + wr * 64 + mf * 16 + lr * 4;
          int bb = gm >> 10, tt = gm & 1023;
          ushort4 pk;
          pk.x = f2bf(acc[mf][nf][0] + bia);
          pk.y = f2bf(acc[mf][nf][1] + bia);
          pk.z = f2bf(acc[mf][nf][2] + bia);
          pk.w = f2bf(acc[mf][nf][3] + bia);
          *(ushort4*)&vt_ws[((long)(bb * H_ + hh) * HD + dd) * T_ + tt] = pk;
        } else {
          unsigned short* dst = (which == 0) ? q_ws : k_ws;
          float scl = (which == 0) ? 0.18033688011112042f : 1.0f;
#pragma unroll
          for (int i = 0; i < 4; ++i) {
            int gm = m0 + wr * 64 + mf * 16 + lr * 4 + i;
            int bb = gm >> 10, tt = gm & 1023;
            dst[((long)(bb * H_ + hh) * T_ + tt) * HD + dd] =
                f2bf((acc[mf][nf][i] + bia) * scl);
          }
        }
      }
  } else {
#pragma unroll
    for (int mf = 0; mf < 4; ++mf)
#pragma unroll
      for (int nf = 0; nf < 4; ++nf) {
        int gn = n0 + wc * 64 + nf * 16 + lc;
        float bia = bias[gn];
#pragma unroll
        for (int i = 0; i < 4; ++i) {
          int gm = m0 + wr * 64 + mf * 16 + lr * 4 + i;
          long idx = (long)gm * C_ + gn;
          zout[idx] = acc[mf][nf][i] + bia + xres[idx];
        }
      }
  }
}

// ---------------------------------------------------------------- attention
// Q,K: [B*H][T][64] bf16 (Q pre-scaled by log2(e)/8). Vt: [B*H][64][T] bf16.
// 4 waves x 16 q-rows. Double-buffered K/V LDS tiles (64 keys), 2-phase
// schedule: prefetch kt+1 -> compute kt -> one barrier. Softmax in exp2
// domain with wave-group max + defer-max; row-sum l via ones-MFMA.
__global__ __launch_bounds__(256, 4) void k_attn(
    const unsigned short* __restrict__ Qp, const unsigned short* __restrict__ Kp,
    const unsigned short* __restrict__ Vtp, const int* __restrict__ maskp,
    unsigned short* __restrict__ Yp) {
  __shared__ unsigned short Kl[2][64 * 64];  // 2 x 8 KB, [key][d] swizzled
  __shared__ unsigned short Vl[2][64 * 64];  // 2 x 8 KB, [d][key] swizzled
  __shared__ unsigned short Pl[4][16 * 64];  // 8 KB, per-wave [q][key] swizzled
  const int tid = threadIdx.x, lane = tid & 63, w = tid >> 6;
  const int bh = blockIdx.x >> 4, qt = blockIdx.x & 15;
  const int b = bh >> 4, h = bh & 15;
  const int lc = lane & 15, lr = lane >> 4;
  const int q0 = qt * 64 + w * 16;

  const unsigned short* qbase = Qp + ((long)bh * T_ + q0) * HD;
  s16x8 aq0 = *(const s16x8*)(qbase + lc * HD + lr * 8);
  s16x8 aq1 = *(const s16x8*)(qbase + lc * HD + 32 + lr * 8);

  s16x8 ones;
#pragma unroll
  for (int j = 0; j < 8; ++j) ones[j] = (short)0x3F80;  // bf16 1.0

  float m_run = -3e38f;
  f32x4 o[4] = {};
  f32x4 o_l = {};

  const char* kb_g = (const char*)(Kp + (long)bh * T_ * HD);
  const char* vb_g = (const char*)(Vtp + (long)bh * HD * T_);
  const int* mrow = maskp + b * T_;

  // stage one 64-key tile (K: 8KB contiguous; Vt: 64 rows x 128B, stride 2KB)
  auto stage = [&](int buf, int kt) {
#pragma unroll
    for (int it = 0; it < 2; ++it) {
      int f = it * 4096 + w * 1024 + lane * 16;
      int row = f >> 7;
      int swz = (f & 127) ^ ((row & 7) << 4);
      gload_lds16(kb_g + (long)kt * 8192 + (f & ~127) + swz,
                  (char*)Kl[buf] + it * 4096 + w * 1024);
      gload_lds16(vb_g + (long)row * (T_ * 2) + kt * 128 + swz,
                  (char*)Vl[buf] + it * 4096 + w * 1024);
    }
  };

  stage(0, 0);
  __syncthreads();  // drains vmcnt for prologue stage

  int cur = 0;
  for (int kt = 0; kt < T_ / 64; ++kt) {
    if (kt + 1 < T_ / 64) stage(cur ^ 1, kt + 1);  // prefetch under compute

    // S = Q K^T (C layout: col=key (lc), row=q (lr*4+i)); exp2 domain
    f32x4 s[4];
#pragma unroll
    for (int kf = 0; kf < 4; ++kf) {
      int key = kf * 16 + lc;
      const char* kl = (const char*)Kl[cur];
      s16x8 kb0 = *(const s16x8*)(kl + ((key * 128 + lr * 16) ^ ((key & 7) << 4)));
      s16x8 kb1 = *(const s16x8*)(kl + ((key * 128 + 64 + lr * 16) ^ ((key & 7) << 4)));
      f32x4 z = {};
      z = __builtin_amdgcn_mfma_f32_16x16x32_bf16(aq0, kb0, z, 0, 0, 0);
      z = __builtin_amdgcn_mfma_f32_16x16x32_bf16(aq1, kb1, z, 0, 0, 0);
      int mv = mrow[kt * 64 + key];
#pragma unroll
      for (int i = 0; i < 4; ++i) s[kf][i] = mv ? z[i] : -1e9f;
    }

    // wave-group max (legal: mask is per-key, shared by all q rows)
    float t0 = s[0][0];
#pragma unroll
    for (int kf = 0; kf < 4; ++kf)
#pragma unroll
      for (int i = 0; i < 4; ++i) t0 = fmaxf(t0, s[kf][i]);
#pragma unroll
    for (int d = 1; d < 64; d <<= 1) t0 = fmaxf(t0, __shfl_xor(t0, d, 64));

    // defer-max: rescale only when max grows by > 8 (P bounded by 2^8)
    if (t0 > m_run + 8.0f) {
      float sc = __builtin_amdgcn_exp2f(m_run - t0);
      m_run = t0;
#pragma unroll
      for (int nf = 0; nf < 4; ++nf)
#pragma unroll
        for (int i = 0; i < 4; ++i) o[nf][i] *= sc;
#pragma unroll
      for (int i = 0; i < 4; ++i) o_l[i] *= sc;
    }

    // P = exp2(S - m), write bf16 to per-wave LDS (swizzled)
    unsigned short* pw = Pl[w];
#pragma unroll
    for (int kf = 0; kf < 4; ++kf) {
      int key2 = (kf * 16 + lc) * 2;
#pragma unroll
      for (int i = 0; i < 4; ++i) {
        float pv = __builtin_amdgcn_exp2f(s[kf][i] - m_run);
        int row = lr * 4 + i;
        *(unsigned short*)((char*)pw + ((row * 128 + key2) ^ ((row & 7) << 4))) =
            f2bf(pv);
      }
    }

    // PV MFMAs + l accumulation via ones column
#pragma unroll
    for (int kc = 0; kc < 2; ++kc) {
      int koff = kc * 64 + lr * 16;
      s16x8 ap = *(const s16x8*)((const char*)pw +
                                 ((lc * 128 + koff) ^ ((lc & 7) << 4)));
      o_l = __builtin_amdgcn_mfma_f32_16x16x32_bf16(ap, ones, o_l, 0, 0, 0);
#pragma unroll
      for (int nf = 0; nf < 4; ++nf) {
        int drow = nf * 16 + lc;
        s16x8 vb = *(const s16x8*)((const char*)Vl[cur] +
                                   ((drow * 128 + koff) ^ ((drow & 7) << 4)));
        o[nf] = __builtin_amdgcn_mfma_f32_16x16x32_bf16(ap, vb, o[nf], 0, 0, 0);
      }
    }
    __syncthreads();  // staged kt+1 landed; safe to flip buffers
    cur ^= 1;
  }

  // normalize + write y [B,T,C] bf16
  float rl[4];
#pragma unroll
  for (int i = 0; i < 4; ++i) rl[i] = 1.0f / o_l[i];
  unsigned short* yb = Yp + ((long)(b * T_ + q0)) * C_ + h * 64;
#pragma unroll
  for (int nf = 0; nf < 4; ++nf) {
    int d = nf * 16 + lc;
#pragma unroll
    for (int i = 0; i < 4; ++i) {
      int qrow = lr * 4 + i;
      yb[(long)qrow * C_ + d] = f2bf(o[nf][i] * rl[i]);
    }
  }
}

// ---------------------------------------------------------------- LayerNorm
__global__ __launch_bounds__(256) void k_ln(const float* __restrict__ z,
                                            const float* __restrict__ lw,
                                            const float* __restrict__ lb,
                                            float* __restrict__ out) {
  const int row = blockIdx.x;
  float4 v = ((const float4*)(z + (long)row * C_))[threadIdx.x];
  float s = v.x + v.y + v.z + v.w;
  float s2 = v.x * v.x + v.y * v.y + v.z * v.z + v.w * v.w;
#pragma unroll
  for (int d = 1; d < 64; d <<= 1) {
    s += __shfl_xor(s, d, 64);
    s2 += __shfl_xor(s2, d, 64);
  }
  __shared__ float rs[4], rq[4];
  int wv_ = threadIdx.x >> 6;
  if ((threadIdx.x & 63) == 0) { rs[wv_] = s; rq[wv_] = s2; }
  __syncthreads();
  s = rs[0] + rs[1] + rs[2] + rs[3];
  s2 = rq[0] + rq[1] + rq[2] + rq[3];
  float mu = s * (1.0f / C_);
  float var = s2 * (1.0f / C_) - mu * mu;
  float inv = rsqrtf(var + 1e-12f);
  float4 wv4 = ((const float4*)lw)[threadIdx.x];
  float4 bv4 = ((const float4*)lb)[threadIdx.x];
  float4 ov;
  ov.x = (v.x - mu) * inv * wv4.x + bv4.x;
  ov.y = (v.y - mu) * inv * wv4.y + bv4.y;
  ov.z = (v.z - mu) * inv * wv4.z + bv4.z;
  ov.w = (v.w - mu) * inv * wv4.w + bv4.w;
  ((float4*)(out + (long)row * C_))[threadIdx.x] = ov;
}

// ---------------------------------------------------------------- launch
extern "C" void kernel_launch(void* const* d_in, const int* in_sizes, int n_in,
                              void* d_out, int out_size, void* d_ws,
                              size_t ws_size, hipStream_t stream) {
  const float* x = (const float*)d_in[0];
  const int* mask = (const int*)d_in[1];
  const float* Wq = (const float*)d_in[2];
  const float* bq = (const float*)d_in[3];
  const float* Wk = (const float*)d_in[4];
  const float* bk = (const float*)d_in[5];
  const float* Wv = (const float*)d_in[6];
  const float* bv = (const float*)d_in[7];
  const float* Wp = (const float*)d_in[8];
  const float* bp = (const float*)d_in[9];
  const float* lnw = (const float*)d_in[10];
  const float* lnb = (const float*)d_in[11];
  float* out = (float*)d_out;

  char* ws = (char*)d_ws;
  const size_t MB = 1024 * 1024;
  unsigned short* xb = (unsigned short*)(ws);             // 16 MB
  unsigned short* q_ws = (unsigned short*)(ws + 16 * MB); // 16 MB
  unsigned short* k_ws = (unsigned short*)(ws + 32 * MB); // 16 MB
  unsigned short* vt_ws = (unsigned short*)(ws + 48 * MB);// 16 MB
  unsigned short* y_ws = (unsigned short*)(ws + 64 * MB); // 16 MB
  unsigned short* wqkv = (unsigned short*)(ws + 80 * MB); // 6 MB
  unsigned short* wpb = (unsigned short*)(ws + 86 * MB);  // 2 MB
  float* bias_cat = (float*)(ws + 88 * MB);               // 12 KB
  float* z = (float*)(ws);  // 32 MB, aliases xb+q_ws (both dead by then)

  k_convert<<<dim3(2048), dim3(256), 0, stream>>>(x, Wq, Wk, Wv, Wp, bq, bk, bv,
                                                  xb, wqkv, wpb, bias_cat);
  k_gemm<0><<<dim3(24, 64), dim3(256), 0, stream>>>(
      xb, wqkv, bias_cat, q_ws, k_ws, vt_ws, nullptr, nullptr);
  k_attn<<<dim3(2048), dim3(256), 0, stream>>>(q_ws, k_ws, vt_ws, mask, y_ws);
  k_gemm<1><<<dim3(8, 64), dim3(256), 0, stream>>>(
      y_ws, wpb, bp, nullptr, nullptr, nullptr, x, z);
  k_ln<<<dim3(8192), dim3(256), 0, stream>>>(z, lnw, lnb, out);
}